// Round 7
// baseline (502.634 us; speedup 1.0000x reference)
//
#include <hip/hip_runtime.h>
#include <stdint.h>

// ActorCritic fused kernels for MI355X (gfx950). Round 7.
//   R6 post-mortem: spill fixed (WRITE 63.8->6.7MB) but time flat at ~231 us/kernel;
//   per-chunk/CU time constant ~5us across R3/R4/R6 and critic(2 blk/CU) == actor
//   (1 blk/CU) => shared-pipe-bound, and the only pipe whose arithmetic fits is
//   DS/LDS (~470KB/chunk: act1 re-read x8 =256KB, act2 96KB, W2 32-64KB, W0 49KB).
//   R7 A/B: actor UNCHANGED (control). Critic (treatment): head fused into GEMM1
//   epilogue in f32 regs (relu(acc+b1)*w2 + red16 over l15 + 2KB valbuf + wave0
//   atomics) -- deletes act2 (96KB) and W2 reads (64KB), 2 barriers/chunk.
//   Predict: critic ~165-185us if DS-bound; flat => theory falsified.

typedef __attribute__((ext_vector_type(8))) short bf16x8;
typedef __attribute__((ext_vector_type(4))) float f32x4;
typedef __attribute__((ext_vector_type(4))) uint32_t u32x4;

#define NROWS    800000
#define NCHUNK   12500      // NROWS / 64
#define OUT_ENT  800000
#define OUT_VP   800001     // 1024 floats (G=64 x S=16)
#define OUT_MASK 801025     // 800000 floats

#define SWZ(row) ((((row) & 7) << 4) ^ (((row) & 16) << 1))

__device__ __forceinline__ short f2bf(float x) {            // RNE float->bf16
  union { float f; uint32_t u; } v; v.f = x;
  return (short)(uint16_t)((v.u + 0x7FFFu + ((v.u >> 16) & 1u)) >> 16);
}
__device__ __forceinline__ float bf2f(short h) {
  union { uint32_t u; float f; } v; v.u = ((uint32_t)(uint16_t)h) << 16;
  return v.f;
}
// DPP helpers (VALU pipe). quad_perm(1,0,3,2)=0xB1, quad_perm(2,3,0,1)=0x4E,
// ROW_ROR:4=0x124, ROW_ROR:8=0x128.
template <int C>
__device__ __forceinline__ float dppf(float x) {
  int r = __builtin_amdgcn_update_dpp(0, __builtin_bit_cast(int, x), C, 0xF, 0xF, true);
  return __builtin_bit_cast(float, r);
}
__device__ __forceinline__ float red16_sum(float x) {
  x += dppf<0xB1>(x); x += dppf<0x4E>(x); x += dppf<0x124>(x); x += dppf<0x128>(x); return x;
}
__device__ __forceinline__ float red16_max(float x) {
  x = fmaxf(x, dppf<0xB1>(x)); x = fmaxf(x, dppf<0x4E>(x));
  x = fmaxf(x, dppf<0x124>(x)); x = fmaxf(x, dppf<0x128>(x)); return x;
}
__device__ __forceinline__ uint32_t cvt_pk_bf16(float a, float b) {   // lo=bf16(a), hi=bf16(b)
  uint32_t r; asm("v_cvt_pk_bf16_f32 %0, %1, %2" : "=v"(r) : "v"(a), "v"(b)); return r;
}

__global__ void zero_kernel(float* out, float* wsf) {
  int t = threadIdx.x + blockIdx.x * blockDim.x;
  for (int i = t; i < 1025; i += 1024) out[OUT_ENT + i] = 0.0f;
  if (t == 0) { wsf[0] = 0.0f; wsf[1] = 0.0f; }
}
__global__ void final_kernel(float* out, const float* wsf) {
  if (threadIdx.x == 0 && blockIdx.x == 0)
    out[OUT_ENT] = (wsf[1] > 0.0f) ? (wsf[0] / wsf[1]) : 0.0f;
}

// ---------------- actor LDS (78848 B) -- UNCHANGED from R6 (control) ----------------
#define A_ACT1 0          // [64][256] bf16 swizzled (32768)
#define A_ACT2 32768      // [64][256] bf16 swizzled (32768)
#define A_W2H  65536      // [16][256] bf16 swizzled (8192)
#define A_W0   73728      // [2][256] f32 (2048)
#define A_B0   75776      // [256] f32 (1024)
#define A_OB   76800      // 2 x [192(+pad)] f32 (2048)
#define A_SZ   78848

__global__ void __launch_bounds__(512, 2) ac_actor(
    const float* __restrict__ ob, const int* __restrict__ action,
    const float* __restrict__ aW0, const float* __restrict__ ab0,
    const float* __restrict__ aW1, const float* __restrict__ ab1,
    const float* __restrict__ aW2, const float* __restrict__ ab2,
    float* __restrict__ out, float* __restrict__ wsf)
{
  extern __shared__ char smem[];
  float* w0buf = (float*)(smem + A_W0);
  float* b0buf = (float*)(smem + A_B0);
  float* obufA = (float*)(smem + A_OB);          // two 256-float buffers
  const f32x4* w04 = (const f32x4*)(smem + A_W0);
  const f32x4* b04 = (const f32x4*)(smem + A_B0);
  __shared__ float went[8], wmf[8];

  const int tid = threadIdx.x, lane = tid & 63, wave = tid >> 6;
  const int l15 = lane & 15, l4 = lane >> 4;

  // setup
  w0buf[tid] = aW0[tid];
  if (tid < 256) b0buf[tid] = ab0[tid];
  for (int id = tid; id < 4096; id += 512) {      // W2 hi -> swizzled LDS
    int n = id >> 8, k = id & 255;
    *(short*)(smem + A_W2H + n * 512 + ((k * 2) ^ SWZ(n))) = f2bf(aW2[k * 16 + n]);
  }
  const int colbase = wave * 32;
  float b1lane[2] = { ab1[colbase + l15], ab1[colbase + 16 + l15] };
  float b2lane = ab2[l15];
  bf16x8 bh[2][8];                                // W1 hi fragments, register-resident
  #pragma unroll
  for (int ct = 0; ct < 2; ++ct) {
    const int n = colbase + ct * 16 + l15;
    #pragma unroll
    for (int ks = 0; ks < 8; ++ks) {
      const int k0 = ks * 32 + 8 * l4;
      bf16x8 h8;
      #pragma unroll
      for (int j = 0; j < 8; ++j) h8[j] = f2bf(aW1[(k0 + j) * 256 + n]);
      bh[ct][ks] = h8;
    }
  }
  // prologue: land chunk c0 into buf 0, start load of c0+stride
  const int c0 = blockIdx.x, stride = gridDim.x;
  float sob = 0.0f;
  if (tid < 192) { obufA[tid] = ob[c0 * 192 + tid]; }
  { int cn = c0 + stride; if (cn < NCHUNK && tid < 192) sob = ob[cn * 192 + tid]; }
  __syncthreads();

  float entacc = 0.0f, mfacc = 0.0f;
  int buf = 0;
  for (int c = c0; c < NCHUNK; c += stride, buf ^= 1) {
    const int row0 = c * 64;
    const float* ocur = obufA + buf * 256;
    float* onxt = (float*)(obufA + (buf ^ 1) * 256);

    // --- P2: mask out + act1 = relu(h@W0+b0); stage next ob ---
    if (tid < 64) out[OUT_MASK + row0 + tid] = ((int)ocur[tid * 3] == 0) ? 1.0f : 0.0f;
    {
      const int kb = tid & 31;
      f32x4 wa0 = w04[kb * 2], wa1 = w04[kb * 2 + 1];
      f32x4 wb0 = w04[64 + kb * 2], wb1 = w04[64 + kb * 2 + 1];
      f32x4 ba0 = b04[kb * 2], ba1 = b04[kb * 2 + 1];
      #pragma unroll
      for (int i = 0; i < 4; ++i) {
        int row = wave * 2 + 16 * i + (lane >> 5);
        float h0 = ocur[row * 3 + 1], h1 = ocur[row * 3 + 2];
        f32x4 va, vb;
        #pragma unroll
        for (int j = 0; j < 4; ++j) {
          va[j] = fmaxf(fmaf(h0, wa0[j], fmaf(h1, wb0[j], ba0[j])), 0.0f);
          vb[j] = fmaxf(fmaf(h0, wa1[j], fmaf(h1, wb1[j], ba1[j])), 0.0f);
        }
        u32x4 v;
        v[0] = cvt_pk_bf16(va[0], va[1]);
        v[1] = cvt_pk_bf16(va[2], va[3]);
        v[2] = cvt_pk_bf16(vb[0], vb[1]);
        v[3] = cvt_pk_bf16(vb[2], vb[3]);
        *(u32x4*)(smem + A_ACT1 + row * 512 + ((kb * 16) ^ SWZ(row))) = v;
      }
    }
    if (tid < 192) onxt[tid] = sob;               // stage chunk c+stride
    { int c2 = c + 2 * stride; if (c2 < NCHUNK && tid < 192) sob = ob[c2 * 192 + tid]; }
    __syncthreads();                              // B2: act1 + onxt ready

    // --- P3: GEMM1 256x256 + epilogue -> act2 ---
    const bool evn = (l15 & 1) == 0;
    #pragma unroll 1
    for (int rtp = 0; rtp < 2; ++rtp) {
      f32x4 acc[2][2];
      #pragma unroll
      for (int h = 0; h < 2; ++h)
        #pragma unroll
        for (int ct = 0; ct < 2; ++ct) acc[h][ct] = (f32x4){0.f, 0.f, 0.f, 0.f};
      const int rA0 = rtp * 32 + l15, rA1 = rA0 + 16;
      #pragma unroll
      for (int ks = 0; ks < 8; ++ks) {
        const int cb = ks * 64 + 16 * l4;
        bf16x8 a0 = *(const bf16x8*)(smem + A_ACT1 + rA0 * 512 + (cb ^ SWZ(rA0)));
        bf16x8 a1 = *(const bf16x8*)(smem + A_ACT1 + rA1 * 512 + (cb ^ SWZ(rA1)));
        acc[0][0] = __builtin_amdgcn_mfma_f32_16x16x32_bf16(a0, bh[0][ks], acc[0][0], 0, 0, 0);
        acc[0][1] = __builtin_amdgcn_mfma_f32_16x16x32_bf16(a0, bh[1][ks], acc[0][1], 0, 0, 0);
        acc[1][0] = __builtin_amdgcn_mfma_f32_16x16x32_bf16(a1, bh[0][ks], acc[1][0], 0, 0, 0);
        acc[1][1] = __builtin_amdgcn_mfma_f32_16x16x32_bf16(a1, bh[1][ks], acc[1][1], 0, 0, 0);
      }
      #pragma unroll
      for (int ct = 0; ct < 2; ++ct) {
        const int colb = (colbase + ct * 16 + (l15 & ~1)) * 2;
        #pragma unroll
        for (int r = 0; r < 4; ++r) {
          float v0 = fmaxf(acc[0][ct][r] + b1lane[ct], 0.0f);
          float v1 = fmaxf(acc[1][ct][r] + b1lane[ct], 0.0f);
          float n0 = dppf<0xB1>(v0), n1 = dppf<0xB1>(v1);
          uint32_t w = cvt_pk_bf16(evn ? v0 : n1, evn ? n0 : v1);
          int rr = rtp * 32 + (evn ? 0 : 16) + 4 * l4 + r;
          *(uint32_t*)(smem + A_ACT2 + rr * 512 + (colb ^ SWZ(rr))) = w;
        }
      }
    }
    __syncthreads();                              // B3: act2 ready

    // --- P4: head GEMM + log-softmax (waves 0-3) ---
    if (wave < 4) {
      const int rowA = wave * 16 + l15;
      const int swA = SWZ(rowA), swW = SWZ(l15);
      f32x4 ae = {0.f,0.f,0.f,0.f}, ao = {0.f,0.f,0.f,0.f};
      #pragma unroll
      for (int ks = 0; ks < 8; ks += 2) {
        const int cb0 = ks * 64 + 16 * l4, cb1 = cb0 + 64;
        bf16x8 a0 = *(const bf16x8*)(smem + A_ACT2 + rowA * 512 + (cb0 ^ swA));
        bf16x8 a1 = *(const bf16x8*)(smem + A_ACT2 + rowA * 512 + (cb1 ^ swA));
        bf16x8 w0f = *(const bf16x8*)(smem + A_W2H + l15 * 512 + (cb0 ^ swW));
        bf16x8 w1f = *(const bf16x8*)(smem + A_W2H + l15 * 512 + (cb1 ^ swW));
        ae = __builtin_amdgcn_mfma_f32_16x16x32_bf16(a0, w0f, ae, 0, 0, 0);
        ao = __builtin_amdgcn_mfma_f32_16x16x32_bf16(a1, w1f, ao, 0, 0, 0);
      }
      #pragma unroll
      for (int r = 0; r < 4; ++r) {
        const int rl = wave * 16 + 4 * l4 + r;
        float x = ae[r] + ao[r] + b2lane;
        float m = red16_max(x);
        float e = __expf(x - m);
        float s = red16_sum(e);
        float t = red16_sum(e * (x - m));
        float ls = __logf(s);
        float mfr = ((int)ob[(row0 + rl) * 3] == 0) ? 1.0f : 0.0f;
        int av = action[row0 + rl];
        if (l15 == av) out[row0 + rl] = (x - m - ls) * mfr;
        if (l15 == 0) { entacc += (ls - t / s) * mfr; mfacc += mfr; }
      }
    }
    // no end barrier: next P2 touches act1/obuf only (disjoint from P4's act2/W2H
    // reads); obuf buffers are fenced by B2+B3 between write and read.
  }
  // entropy num/den -> global atomics
  #pragma unroll
  for (int d = 1; d < 64; d <<= 1) { entacc += __shfl_xor(entacc, d); mfacc += __shfl_xor(mfacc, d); }
  if (lane == 0) { went[wave] = entacc; wmf[wave] = mfacc; }
  __syncthreads();
  if (tid == 0) {
    float e = 0.f, m = 0.f;
    #pragma unroll
    for (int i = 0; i < 8; ++i) { e += went[i]; m += wmf[i]; }
    atomicAdd(&wsf[0], e); atomicAdd(&wsf[1], m);
  }
}

// ---------------- critic LDS (39936 B) -- R7 treatment: no act2, no W2 LDS ----------------
#define C_ACT1 0          // [64][256] bf16 swizzled (32768)
#define C_W0   32768      // [2][256] f32 (2048)
#define C_B0   34816      // [256] f32 (1024)
#define C_OB   35840      // 2 x 1024
#define C_VB   37888      // [8][64] f32 partial vals (2048)
#define C_SZ   39936

__global__ void __launch_bounds__(512, 2) ac_critic(
    const float* __restrict__ ob, const int* __restrict__ graph_ids,
    const float* __restrict__ cW0, const float* __restrict__ cb0,
    const float* __restrict__ cW1, const float* __restrict__ cb1,
    const float* __restrict__ cW2, const float* __restrict__ cb2,
    float* __restrict__ out)
{
  extern __shared__ char smem[];
  float* w0buf = (float*)(smem + C_W0);
  float* b0buf = (float*)(smem + C_B0);
  float* obufA = (float*)(smem + C_OB);
  float* vbuf  = (float*)(smem + C_VB);
  const f32x4* w04 = (const f32x4*)(smem + C_W0);
  const f32x4* b04 = (const f32x4*)(smem + C_B0);

  const int tid = threadIdx.x, lane = tid & 63, wave = tid >> 6;
  const int l15 = lane & 15, l4 = lane >> 4;

  w0buf[tid] = cW0[tid];
  if (tid < 256) b0buf[tid] = cb0[tid];
  const float cb2v = cb2[0];
  const int colbase = wave * 32;
  float b1lane[2] = { cb1[colbase + l15], cb1[colbase + 16 + l15] };
  const float w2c0 = cW2[colbase + l15];            // head weights for this lane's 2 cols
  const float w2c1 = cW2[colbase + 16 + l15];

  bf16x8 bh[2][8];                                  // W1 hi, register-resident
  #pragma unroll
  for (int ct = 0; ct < 2; ++ct) {
    const int n = colbase + ct * 16 + l15;
    #pragma unroll
    for (int ks = 0; ks < 8; ++ks) {
      const int k0 = ks * 32 + 8 * l4;
      bf16x8 h8;
      #pragma unroll
      for (int j = 0; j < 8; ++j) h8[j] = f2bf(cW1[(k0 + j) * 256 + n]);
      bh[ct][ks] = h8;
    }
  }
  const int c0 = blockIdx.x, stride = gridDim.x;
  float sob = 0.0f;
  if (tid < 192) { obufA[tid] = ob[c0 * 192 + tid]; }
  { int cn = c0 + stride; if (cn < NCHUNK && tid < 192) sob = ob[cn * 192 + tid]; }
  __syncthreads();

  int buf = 0;
  for (int c = c0; c < NCHUNK; c += stride, buf ^= 1) {
    const float* ocur = obufA + buf * 256;
    float* onxt = (float*)(obufA + (buf ^ 1) * 256);

    // --- P2: act1 = relu(h@W0+b0) -> swizzled bf16 LDS; stage next ob ---
    {
      const int kb = tid & 31;
      f32x4 wa0 = w04[kb * 2], wa1 = w04[kb * 2 + 1];
      f32x4 wb0 = w04[64 + kb * 2], wb1 = w04[64 + kb * 2 + 1];
      f32x4 ba0 = b04[kb * 2], ba1 = b04[kb * 2 + 1];
      #pragma unroll
      for (int i = 0; i < 4; ++i) {
        int row = wave * 2 + 16 * i + (lane >> 5);
        float h0 = ocur[row * 3 + 1], h1 = ocur[row * 3 + 2];
        f32x4 va, vb;
        #pragma unroll
        for (int j = 0; j < 4; ++j) {
          va[j] = fmaxf(fmaf(h0, wa0[j], fmaf(h1, wb0[j], ba0[j])), 0.0f);
          vb[j] = fmaxf(fmaf(h0, wa1[j], fmaf(h1, wb1[j], ba1[j])), 0.0f);
        }
        u32x4 v;
        v[0] = cvt_pk_bf16(va[0], va[1]);
        v[1] = cvt_pk_bf16(va[2], va[3]);
        v[2] = cvt_pk_bf16(vb[0], vb[1]);
        v[3] = cvt_pk_bf16(vb[2], vb[3]);
        *(u32x4*)(smem + C_ACT1 + row * 512 + ((kb * 16) ^ SWZ(row))) = v;
      }
    }
    if (tid < 192) onxt[tid] = sob;
    { int c2 = c + 2 * stride; if (c2 < NCHUNK && tid < 192) sob = ob[c2 * 192 + tid]; }
    __syncthreads();                              // B2: act1 + onxt ready

    // mask for wave0's tail work: read ocur BEFORE B3 (next P2 overwrites it)
    float o0w0 = 0.0f;
    if (wave == 0) o0w0 = ocur[lane * 3];

    // --- P3: GEMM1 + fused f32 head epilogue (no act2, no bf16 round-trip) ---
    #pragma unroll 1
    for (int rtp = 0; rtp < 2; ++rtp) {
      f32x4 acc[2][2];
      #pragma unroll
      for (int h = 0; h < 2; ++h)
        #pragma unroll
        for (int ct = 0; ct < 2; ++ct) acc[h][ct] = (f32x4){0.f, 0.f, 0.f, 0.f};
      const int rA0 = rtp * 32 + l15, rA1 = rA0 + 16;
      #pragma unroll
      for (int ks = 0; ks < 8; ++ks) {
        const int cb = ks * 64 + 16 * l4;
        bf16x8 a0 = *(const bf16x8*)(smem + C_ACT1 + rA0 * 512 + (cb ^ SWZ(rA0)));
        bf16x8 a1 = *(const bf16x8*)(smem + C_ACT1 + rA1 * 512 + (cb ^ SWZ(rA1)));
        acc[0][0] = __builtin_amdgcn_mfma_f32_16x16x32_bf16(a0, bh[0][ks], acc[0][0], 0, 0, 0);
        acc[0][1] = __builtin_amdgcn_mfma_f32_16x16x32_bf16(a0, bh[1][ks], acc[0][1], 0, 0, 0);
        acc[1][0] = __builtin_amdgcn_mfma_f32_16x16x32_bf16(a1, bh[0][ks], acc[1][0], 0, 0, 0);
        acc[1][1] = __builtin_amdgcn_mfma_f32_16x16x32_bf16(a1, bh[1][ks], acc[1][1], 0, 0, 0);
      }
      // fused head: per-lane val contribution for its 2 cols, reduce over l15
      #pragma unroll
      for (int h = 0; h < 2; ++h) {
        #pragma unroll
        for (int r = 0; r < 4; ++r) {
          float p = fmaxf(acc[h][0][r] + b1lane[0], 0.0f) * w2c0
                  + fmaxf(acc[h][1][r] + b1lane[1], 0.0f) * w2c1;
          p = red16_sum(p);                       // sum over the 16 l15-lanes (32 cols)
          if (l15 == 0) vbuf[wave * 64 + rtp * 32 + h * 16 + 4 * l4 + r] = p;
        }
      }
    }
    __syncthreads();                              // B3: vbuf ready; act1 free for next P2

    // --- wave 0: cross-wave sum + masked segment-sum atomics (64 rows = 64 lanes) ---
    if (wave == 0) {
      float v = 0.0f;
      #pragma unroll
      for (int w = 0; w < 8; ++w) v += vbuf[w * 64 + lane];
      if ((int)o0w0 == 0) {
        int g = graph_ids[c * 4 + (lane >> 4)];
        atomicAdd(&out[OUT_VP + g * 16 + (lane & 15)], (v + cb2v) * (1.0f / 50000.0f));
      }
    }
    // vbuf reuse fenced by next iteration's B2 (wave0 must reach it first);
    // ocur overwrite is safe: mask was captured into o0w0 before B3.
  }
}

extern "C" void kernel_launch(void* const* d_in, const int* in_sizes, int n_in,
                              void* d_out, int out_size, void* d_ws, size_t ws_size,
                              hipStream_t stream) {
  const float* ob     = (const float*)d_in[0];
  const int*   action = (const int*)d_in[1];
  const int*   gids   = (const int*)d_in[2];
  const float* aW0 = (const float*)d_in[3],  *ab0 = (const float*)d_in[4];
  const float* aW1 = (const float*)d_in[5],  *ab1 = (const float*)d_in[6];
  const float* aW2 = (const float*)d_in[7],  *ab2 = (const float*)d_in[8];
  const float* cW0 = (const float*)d_in[9],  *cb0 = (const float*)d_in[10];
  const float* cW1 = (const float*)d_in[11], *cb1 = (const float*)d_in[12];
  const float* cW2 = (const float*)d_in[13], *cb2 = (const float*)d_in[14];
  float* out = (float*)d_out;
  float* wsf = (float*)d_ws;

  zero_kernel<<<2, 512, 0, stream>>>(out, wsf);
  ac_actor<<<512, 512, A_SZ, stream>>>(ob, action, aW0, ab0, aW1, ab1, aW2, ab2, out, wsf);
  ac_critic<<<512, 512, C_SZ, stream>>>(ob, gids, cW0, cb0, cW1, cb1, cW2, cb2, out);
  final_kernel<<<1, 64, 0, stream>>>(out, wsf);
}

// Round 8
// 479.505 us; speedup vs baseline: 1.0482x; 1.0482x over previous
//
#include <hip/hip_runtime.h>
#include <stdint.h>

// ActorCritic fused kernel for MI355X (gfx950). Round 8.
//   R7 post-mortem: DS-traffic cut was NEUTRAL => not DS-BW-bound. Busy fractions
//   (VALU 43 + MFMA 20 + DS ~15) sum to ~80% but phases are barrier-lockstep, so
//   pipes never overlap => stall-bound. R8: ONE kernel, mixed-role grid (1024
//   blocks, role=(b>>8)&1 so co-resident pairs {i,i+256} get opposite roles) =>
//   actor MFMA overlaps critic VALU on the same CU. Plus: bias folded into acc
//   init; actor P4 split across all 8 waves (2 rows each, head MFMA duplicated).

typedef __attribute__((ext_vector_type(8))) short bf16x8;
typedef __attribute__((ext_vector_type(4))) float f32x4;
typedef __attribute__((ext_vector_type(4))) uint32_t u32x4;

#define NROWS    800000
#define NCHUNK   12500      // NROWS / 64
#define OUT_ENT  800000
#define OUT_VP   800001     // 1024 floats (G=64 x S=16)
#define OUT_MASK 801025     // 800000 floats

#define SWZ(row) ((((row) & 7) << 4) ^ (((row) & 16) << 1))

__device__ __forceinline__ short f2bf(float x) {            // RNE float->bf16
  union { float f; uint32_t u; } v; v.f = x;
  return (short)(uint16_t)((v.u + 0x7FFFu + ((v.u >> 16) & 1u)) >> 16);
}
__device__ __forceinline__ float bf2f(short h) {
  union { uint32_t u; float f; } v; v.u = ((uint32_t)(uint16_t)h) << 16;
  return v.f;
}
// DPP helpers (VALU pipe). quad_perm(1,0,3,2)=0xB1, quad_perm(2,3,0,1)=0x4E,
// ROW_ROR:4=0x124, ROW_ROR:8=0x128.
template <int C>
__device__ __forceinline__ float dppf(float x) {
  int r = __builtin_amdgcn_update_dpp(0, __builtin_bit_cast(int, x), C, 0xF, 0xF, true);
  return __builtin_bit_cast(float, r);
}
__device__ __forceinline__ float red16_sum(float x) {
  x += dppf<0xB1>(x); x += dppf<0x4E>(x); x += dppf<0x124>(x); x += dppf<0x128>(x); return x;
}
__device__ __forceinline__ float red16_max(float x) {
  x = fmaxf(x, dppf<0xB1>(x)); x = fmaxf(x, dppf<0x4E>(x));
  x = fmaxf(x, dppf<0x124>(x)); x = fmaxf(x, dppf<0x128>(x)); return x;
}
__device__ __forceinline__ uint32_t cvt_pk_bf16(float a, float b) {   // lo=bf16(a), hi=bf16(b)
  uint32_t r; asm("v_cvt_pk_bf16_f32 %0, %1, %2" : "=v"(r) : "v"(a), "v"(b)); return r;
}

__global__ void zero_kernel(float* out, float* wsf) {
  int t = threadIdx.x + blockIdx.x * blockDim.x;
  for (int i = t; i < 1025; i += 1024) out[OUT_ENT + i] = 0.0f;
  if (t == 0) { wsf[0] = 0.0f; wsf[1] = 0.0f; }
}
__global__ void final_kernel(float* out, const float* wsf) {
  if (threadIdx.x == 0 && blockIdx.x == 0)
    out[OUT_ENT] = (wsf[1] > 0.0f) ? (wsf[0] / wsf[1]) : 0.0f;
}

// ---------------- merged LDS layout (78848 B) ----------------
#define L_ACT1 0          // [64][256] bf16 swizzled (32768)
#define L_ACT2 32768      // actor: [64][256] bf16 swizzled; critic: vbuf [8][64] f32 (2048 used)
#define L_W2H  65536      // actor: [16][256] bf16 swizzled (8192)
#define L_W0   73728      // [2][256] f32 (2048)
#define L_B0   75776      // [256] f32 (1024)
#define L_OB   76800      // 2 x [192(+pad)] f32 (2048)
#define L_SZ   78848

__global__ void __launch_bounds__(512, 2) ac_main(
    const float* __restrict__ ob, const int* __restrict__ action,
    const int* __restrict__ graph_ids,
    const float* __restrict__ aW0, const float* __restrict__ ab0,
    const float* __restrict__ aW1, const float* __restrict__ ab1,
    const float* __restrict__ aW2, const float* __restrict__ ab2,
    const float* __restrict__ cW0, const float* __restrict__ cb0,
    const float* __restrict__ cW1, const float* __restrict__ cb1,
    const float* __restrict__ cW2, const float* __restrict__ cb2,
    float* __restrict__ out, float* __restrict__ wsf)
{
  extern __shared__ char smem[];
  float* w0buf = (float*)(smem + L_W0);
  float* b0buf = (float*)(smem + L_B0);
  float* obufA = (float*)(smem + L_OB);
  float* vbuf  = (float*)(smem + L_ACT2);        // critic alias
  const f32x4* w04 = (const f32x4*)(smem + L_W0);
  const f32x4* b04 = (const f32x4*)(smem + L_B0);
  __shared__ float went[8], wmf[8];

  const int b = blockIdx.x;
  const int role = (b >> 8) & 1;                 // pairs {i, i+256} -> opposite roles
  const int pid  = (b & 255) | ((b >> 9) << 8);  // each role: pid in [0,512)
  const int stride = 512;

  const int tid = threadIdx.x, lane = tid & 63, wave = tid >> 6;
  const int l15 = lane & 15, l4 = lane >> 4;

  const float* W0s = role ? cW0 : aW0;
  const float* B0s = role ? cb0 : ab0;
  const float* W1s = role ? cW1 : aW1;
  const float* B1s = role ? cb1 : ab1;

  // setup
  w0buf[tid] = W0s[tid];
  if (tid < 256) b0buf[tid] = B0s[tid];
  if (!role) {
    for (int id = tid; id < 4096; id += 512) {    // W2 -> swizzled LDS (actor)
      int n = id >> 8, k = id & 255;
      *(short*)(smem + L_W2H + n * 512 + ((k * 2) ^ SWZ(n))) = f2bf(aW2[k * 16 + n]);
    }
  }
  const int colbase = wave * 32;
  float b1lane[2] = { B1s[colbase + l15], B1s[colbase + 16 + l15] };
  float b2lane = 0.0f, w2c0 = 0.0f, w2c1 = 0.0f, cb2v = 0.0f;
  if (!role) b2lane = ab2[l15];
  else { w2c0 = cW2[colbase + l15]; w2c1 = cW2[colbase + 16 + l15]; cb2v = cb2[0]; }

  bf16x8 bh[2][8];                                // W1 fragments, register-resident
  #pragma unroll
  for (int ct = 0; ct < 2; ++ct) {
    const int n = colbase + ct * 16 + l15;
    #pragma unroll
    for (int ks = 0; ks < 8; ++ks) {
      const int k0 = ks * 32 + 8 * l4;
      bf16x8 h8;
      #pragma unroll
      for (int j = 0; j < 8; ++j) h8[j] = f2bf(W1s[(k0 + j) * 256 + n]);
      bh[ct][ks] = h8;
    }
  }
  // prologue: land chunk pid into buf 0, start load of pid+stride
  float sob = 0.0f;
  if (tid < 192) { obufA[tid] = ob[pid * 192 + tid]; }
  { int cn = pid + stride; if (cn < NCHUNK && tid < 192) sob = ob[cn * 192 + tid]; }
  __syncthreads();

  float entacc = 0.0f, mfacc = 0.0f;
  int buf = 0;
  for (int c = pid; c < NCHUNK; c += stride, buf ^= 1) {
    const int row0 = c * 64;
    const float* ocur = obufA + buf * 256;
    float* onxt = (float*)(obufA + (buf ^ 1) * 256);

    // --- P2: [actor: mask out] + act1 = relu(h@W0+b0); stage next ob ---
    if (!role && tid < 64)
      out[OUT_MASK + row0 + tid] = ((int)ocur[tid * 3] == 0) ? 1.0f : 0.0f;
    {
      const int kb = tid & 31;
      f32x4 wa0 = w04[kb * 2], wa1 = w04[kb * 2 + 1];
      f32x4 wb0 = w04[64 + kb * 2], wb1 = w04[64 + kb * 2 + 1];
      f32x4 ba0 = b04[kb * 2], ba1 = b04[kb * 2 + 1];
      #pragma unroll
      for (int i = 0; i < 4; ++i) {
        int row = wave * 2 + 16 * i + (lane >> 5);
        float h0 = ocur[row * 3 + 1], h1 = ocur[row * 3 + 2];
        f32x4 va, vb;
        #pragma unroll
        for (int j = 0; j < 4; ++j) {
          va[j] = fmaxf(fmaf(h0, wa0[j], fmaf(h1, wb0[j], ba0[j])), 0.0f);
          vb[j] = fmaxf(fmaf(h0, wa1[j], fmaf(h1, wb1[j], ba1[j])), 0.0f);
        }
        u32x4 v;
        v[0] = cvt_pk_bf16(va[0], va[1]);
        v[1] = cvt_pk_bf16(va[2], va[3]);
        v[2] = cvt_pk_bf16(vb[0], vb[1]);
        v[3] = cvt_pk_bf16(vb[2], vb[3]);
        *(u32x4*)(smem + L_ACT1 + row * 512 + ((kb * 16) ^ SWZ(row))) = v;
      }
    }
    if (tid < 192) onxt[tid] = sob;
    { int c2 = c + 2 * stride; if (c2 < NCHUNK && tid < 192) sob = ob[c2 * 192 + tid]; }
    __syncthreads();                              // B2: act1 + onxt ready

    // critic: capture mask before B3 (ocur reused later)
    float o0w0 = 0.0f;
    if (role && wave == 0) o0w0 = ocur[lane * 3];

    // --- P3: GEMM1 (acc init = b1) + role epilogue ---
    const bool evn = (l15 & 1) == 0;
    #pragma unroll 1
    for (int rtp = 0; rtp < 2; ++rtp) {
      f32x4 acc[2][2];
      #pragma unroll
      for (int h = 0; h < 2; ++h)
        #pragma unroll
        for (int ct = 0; ct < 2; ++ct)
          acc[h][ct] = (f32x4){b1lane[ct], b1lane[ct], b1lane[ct], b1lane[ct]};
      const int rA0 = rtp * 32 + l15, rA1 = rA0 + 16;
      #pragma unroll
      for (int ks = 0; ks < 8; ++ks) {
        const int cb = ks * 64 + 16 * l4;
        bf16x8 a0 = *(const bf16x8*)(smem + L_ACT1 + rA0 * 512 + (cb ^ SWZ(rA0)));
        bf16x8 a1 = *(const bf16x8*)(smem + L_ACT1 + rA1 * 512 + (cb ^ SWZ(rA1)));
        acc[0][0] = __builtin_amdgcn_mfma_f32_16x16x32_bf16(a0, bh[0][ks], acc[0][0], 0, 0, 0);
        acc[0][1] = __builtin_amdgcn_mfma_f32_16x16x32_bf16(a0, bh[1][ks], acc[0][1], 0, 0, 0);
        acc[1][0] = __builtin_amdgcn_mfma_f32_16x16x32_bf16(a1, bh[0][ks], acc[1][0], 0, 0, 0);
        acc[1][1] = __builtin_amdgcn_mfma_f32_16x16x32_bf16(a1, bh[1][ks], acc[1][1], 0, 0, 0);
      }
      if (!role) {
        // actor epilogue: relu -> packed bf16 act2
        #pragma unroll
        for (int ct = 0; ct < 2; ++ct) {
          const int colb = (colbase + ct * 16 + (l15 & ~1)) * 2;
          #pragma unroll
          for (int r = 0; r < 4; ++r) {
            float v0 = fmaxf(acc[0][ct][r], 0.0f);
            float v1 = fmaxf(acc[1][ct][r], 0.0f);
            float n0 = dppf<0xB1>(v0), n1 = dppf<0xB1>(v1);
            uint32_t w = cvt_pk_bf16(evn ? v0 : n1, evn ? n0 : v1);
            int rr = rtp * 32 + (evn ? 0 : 16) + 4 * l4 + r;
            *(uint32_t*)(smem + L_ACT2 + rr * 512 + (colb ^ SWZ(rr))) = w;
          }
        }
      } else {
        // critic epilogue: fused f32 head, reduce over l15, partials -> vbuf
        #pragma unroll
        for (int h = 0; h < 2; ++h) {
          #pragma unroll
          for (int r = 0; r < 4; ++r) {
            float p = fmaxf(acc[h][0][r], 0.0f) * w2c0
                    + fmaxf(acc[h][1][r], 0.0f) * w2c1;
            p = red16_sum(p);
            if (l15 == 0) vbuf[wave * 64 + rtp * 32 + h * 16 + 4 * l4 + r] = p;
          }
        }
      }
    }
    __syncthreads();                              // B3: act2 / vbuf ready

    // --- P4 ---
    if (!role) {
      // actor head on ALL 8 waves: rt = wave&3, each wave softmaxes 2 rows
      const int rt = wave & 3, half = wave >> 2;
      const int rowA = rt * 16 + l15;
      const int swA = SWZ(rowA), swW = SWZ(l15);
      f32x4 ae = {b2lane, b2lane, b2lane, b2lane}, ao = {0.f,0.f,0.f,0.f};
      #pragma unroll
      for (int ks = 0; ks < 8; ks += 2) {
        const int cb0 = ks * 64 + 16 * l4, cb1 = cb0 + 64;
        bf16x8 a0 = *(const bf16x8*)(smem + L_ACT2 + rowA * 512 + (cb0 ^ swA));
        bf16x8 a1 = *(const bf16x8*)(smem + L_ACT2 + rowA * 512 + (cb1 ^ swA));
        bf16x8 w0f = *(const bf16x8*)(smem + L_W2H + l15 * 512 + (cb0 ^ swW));
        bf16x8 w1f = *(const bf16x8*)(smem + L_W2H + l15 * 512 + (cb1 ^ swW));
        ae = __builtin_amdgcn_mfma_f32_16x16x32_bf16(a0, w0f, ae, 0, 0, 0);
        ao = __builtin_amdgcn_mfma_f32_16x16x32_bf16(a1, w1f, ao, 0, 0, 0);
      }
      #pragma unroll
      for (int r2 = 0; r2 < 2; ++r2) {
        const int r = half * 2 + r2;
        const int rl = rt * 16 + 4 * l4 + r;
        float x = ae[r] + ao[r];
        float m = red16_max(x);
        float e = __expf(x - m);
        float s = red16_sum(e);
        float t = red16_sum(e * (x - m));
        float ls = __logf(s);
        float mfr = ((int)ob[(row0 + rl) * 3] == 0) ? 1.0f : 0.0f;
        int av = action[row0 + rl];
        if (l15 == av) out[row0 + rl] = (x - m - ls) * mfr;
        if (l15 == 0) { entacc += (ls - t / s) * mfr; mfacc += mfr; }
      }
    } else {
      // critic: wave 0 sums partials + masked segment-sum atomics
      if (wave == 0) {
        float v = 0.0f;
        #pragma unroll
        for (int w = 0; w < 8; ++w) v += vbuf[w * 64 + lane];
        if ((int)o0w0 == 0) {
          int g = graph_ids[c * 4 + (lane >> 4)];
          atomicAdd(&out[OUT_VP + g * 16 + (lane & 15)], (v + cb2v) * (1.0f / 50000.0f));
        }
      }
    }
    // no end barrier: next P2 writes act1/obuf only; act2/W2H/vbuf reads by P4 are
    // disjoint from those; vbuf reuse and obuf reuse fenced by next B2 (see R7).
  }
  // entropy num/den -> global atomics (actor blocks only; block-uniform branch)
  if (!role) {
    #pragma unroll
    for (int d = 1; d < 64; d <<= 1) { entacc += __shfl_xor(entacc, d); mfacc += __shfl_xor(mfacc, d); }
    if (lane == 0) { went[wave] = entacc; wmf[wave] = mfacc; }
    __syncthreads();
    if (tid == 0) {
      float e = 0.f, m = 0.f;
      #pragma unroll
      for (int i = 0; i < 8; ++i) { e += went[i]; m += wmf[i]; }
      atomicAdd(&wsf[0], e); atomicAdd(&wsf[1], m);
    }
  }
}

extern "C" void kernel_launch(void* const* d_in, const int* in_sizes, int n_in,
                              void* d_out, int out_size, void* d_ws, size_t ws_size,
                              hipStream_t stream) {
  const float* ob     = (const float*)d_in[0];
  const int*   action = (const int*)d_in[1];
  const int*   gids   = (const int*)d_in[2];
  const float* aW0 = (const float*)d_in[3],  *ab0 = (const float*)d_in[4];
  const float* aW1 = (const float*)d_in[5],  *ab1 = (const float*)d_in[6];
  const float* aW2 = (const float*)d_in[7],  *ab2 = (const float*)d_in[8];
  const float* cW0 = (const float*)d_in[9],  *cb0 = (const float*)d_in[10];
  const float* cW1 = (const float*)d_in[11], *cb1 = (const float*)d_in[12];
  const float* cW2 = (const float*)d_in[13], *cb2 = (const float*)d_in[14];
  float* out = (float*)d_out;
  float* wsf = (float*)d_ws;

  zero_kernel<<<2, 512, 0, stream>>>(out, wsf);
  ac_main<<<1024, 512, L_SZ, stream>>>(ob, action, gids, aW0, ab0, aW1, ab1, aW2, ab2,
                                       cW0, cb0, cW1, cb1, cW2, cb2, out, wsf);
  final_kernel<<<1, 64, 0, stream>>>(out, wsf);
}

// Round 9
// 456.055 us; speedup vs baseline: 1.1021x; 1.0514x over previous
//
#include <hip/hip_runtime.h>
#include <stdint.h>

// ActorCritic fused kernel for MI355X (gfx950). Round 9.
//   R8 post-mortem: merge neutral (occupancy stuck at 1 block/CU -> no overlap).
//   Invariant across R3-R8: ~4.5us/chunk/CU, VALU 42% / MFMA 21% phase-lockstep.
//   => shorten VALU phases: (1) layer-0 via MFMA (transposed trick, W0-frag const,
//   b0 folded into C-init); (2) transposed GEMM1 (mfma(bh,a)) so the epilogue
//   packs within-lane (2 cvt_pk + b64, no DPP/select cross-lane dance), b1 folded;
//   (3) P4 masks captured from LDS pre-B3 (no global ob re-read).
//   W0/B0 LDS staging deleted (LDS 78848 -> 75776).

typedef __attribute__((ext_vector_type(8))) short bf16x8;
typedef __attribute__((ext_vector_type(4))) float f32x4;
typedef __attribute__((ext_vector_type(2))) uint32_t u32x2;
typedef __attribute__((ext_vector_type(4))) uint32_t u32x4;

#define NROWS    800000
#define NCHUNK   12500      // NROWS / 64
#define OUT_ENT  800000
#define OUT_VP   800001     // 1024 floats (G=64 x S=16)
#define OUT_MASK 801025     // 800000 floats

#define SWZ(row) ((((row) & 7) << 4) ^ (((row) & 16) << 1))

__device__ __forceinline__ short f2bf(float x) {            // RNE float->bf16
  union { float f; uint32_t u; } v; v.f = x;
  return (short)(uint16_t)((v.u + 0x7FFFu + ((v.u >> 16) & 1u)) >> 16);
}
// DPP helpers (VALU pipe). quad_perm(1,0,3,2)=0xB1, quad_perm(2,3,0,1)=0x4E,
// ROW_ROR:4=0x124, ROW_ROR:8=0x128.
template <int C>
__device__ __forceinline__ float dppf(float x) {
  int r = __builtin_amdgcn_update_dpp(0, __builtin_bit_cast(int, x), C, 0xF, 0xF, true);
  return __builtin_bit_cast(float, r);
}
__device__ __forceinline__ float red16_sum(float x) {
  x += dppf<0xB1>(x); x += dppf<0x4E>(x); x += dppf<0x124>(x); x += dppf<0x128>(x); return x;
}
__device__ __forceinline__ float red16_max(float x) {
  x = fmaxf(x, dppf<0xB1>(x)); x = fmaxf(x, dppf<0x4E>(x));
  x = fmaxf(x, dppf<0x124>(x)); x = fmaxf(x, dppf<0x128>(x)); return x;
}
__device__ __forceinline__ uint32_t cvt_pk_bf16(float a, float b) {   // lo=bf16(a), hi=bf16(b)
  uint32_t r; asm("v_cvt_pk_bf16_f32 %0, %1, %2" : "=v"(r) : "v"(a), "v"(b)); return r;
}
__device__ __forceinline__ bf16x8 frag_u32(uint32_t a, uint32_t b, uint32_t c, uint32_t d) {
  union { u32x4 u; bf16x8 h; } v; v.u = (u32x4){a, b, c, d}; return v.h;
}

__global__ void zero_kernel(float* out, float* wsf) {
  int t = threadIdx.x + blockIdx.x * blockDim.x;
  for (int i = t; i < 1025; i += 1024) out[OUT_ENT + i] = 0.0f;
  if (t == 0) { wsf[0] = 0.0f; wsf[1] = 0.0f; }
}
__global__ void final_kernel(float* out, const float* wsf) {
  if (threadIdx.x == 0 && blockIdx.x == 0)
    out[OUT_ENT] = (wsf[1] > 0.0f) ? (wsf[0] / wsf[1]) : 0.0f;
}

// ---------------- merged LDS layout (75776 B) ----------------
#define L_ACT1 0          // [64][256] bf16 swizzled (32768)
#define L_ACT2 32768      // actor: [64][256] bf16 swizzled; critic: vbuf [8][64] f32
#define L_W2H  65536      // actor: [16][256] bf16 swizzled (8192)
#define L_OB   73728      // 2 x [192(+pad)] f32 (2048)
#define L_SZ   75776

__global__ void __launch_bounds__(512, 2) ac_main(
    const float* __restrict__ ob, const int* __restrict__ action,
    const int* __restrict__ graph_ids,
    const float* __restrict__ aW0, const float* __restrict__ ab0,
    const float* __restrict__ aW1, const float* __restrict__ ab1,
    const float* __restrict__ aW2, const float* __restrict__ ab2,
    const float* __restrict__ cW0, const float* __restrict__ cb0,
    const float* __restrict__ cW1, const float* __restrict__ cb1,
    const float* __restrict__ cW2, const float* __restrict__ cb2,
    float* __restrict__ out, float* __restrict__ wsf)
{
  extern __shared__ char smem[];
  float* obufA = (float*)(smem + L_OB);
  float* vbuf  = (float*)(smem + L_ACT2);        // critic alias
  __shared__ float went[8], wmf[8];

  const int b = blockIdx.x;
  const int role = (b >> 8) & 1;                 // pairs {i, i+256} -> opposite roles
  const int pid  = (b & 255) | ((b >> 9) << 8);  // each role: pid in [0,512)
  const int stride = 512;

  const int tid = threadIdx.x, lane = tid & 63, wave = tid >> 6;
  const int l15 = lane & 15, l4 = lane >> 4;

  const float* W0s = role ? cW0 : aW0;
  const float* B0s = role ? cb0 : ab0;
  const float* W1s = role ? cW1 : aW1;
  const float* B1s = role ? cb1 : ab1;

  const int colbase = wave * 32;

  // W0 A-frags (constant): only l4==0 lanes carry k=0,1 = {W0[0][col], W0[1][col]}
  bf16x8 w0f[2];
  #pragma unroll
  for (int ct = 0; ct < 2; ++ct) {
    int coln = colbase + ct * 16 + l15;
    uint32_t p = 0u;
    if (l4 == 0) p = cvt_pk_bf16(W0s[coln], W0s[256 + coln]);
    w0f[ct] = frag_u32(p, 0u, 0u, 0u);
  }
  // bias C-inits: index = colbase + ct*16 + 4*l4 + r
  f32x4 b0i[2], b1i[2], w2r[2];
  #pragma unroll
  for (int ct = 0; ct < 2; ++ct)
    #pragma unroll
    for (int r = 0; r < 4; ++r) {
      int idx = colbase + ct * 16 + 4 * l4 + r;
      b0i[ct][r] = B0s[idx];
      b1i[ct][r] = B1s[idx];
      w2r[ct][r] = role ? cW2[idx] : 0.0f;
    }
  float b2lane = 0.0f, cb2v = 0.0f;
  if (!role) {
    b2lane = ab2[l15];
    for (int id = tid; id < 4096; id += 512) {    // W2 -> swizzled LDS (actor)
      int n = id >> 8, k = id & 255;
      *(short*)(smem + L_W2H + n * 512 + ((k * 2) ^ SWZ(n))) = f2bf(aW2[k * 16 + n]);
    }
  } else cb2v = cb2[0];

  bf16x8 bh[2][8];                                // W1 fragments, register-resident
  #pragma unroll
  for (int ct = 0; ct < 2; ++ct) {
    const int n = colbase + ct * 16 + l15;
    #pragma unroll
    for (int ks = 0; ks < 8; ++ks) {
      const int k0 = ks * 32 + 8 * l4;
      bf16x8 h8;
      #pragma unroll
      for (int j = 0; j < 8; ++j) h8[j] = f2bf(W1s[(k0 + j) * 256 + n]);
      bh[ct][ks] = h8;
    }
  }
  // prologue: land chunk pid into buf 0, start load of pid+stride
  float sob = 0.0f;
  if (tid < 192) { obufA[tid] = ob[pid * 192 + tid]; }
  { int cn = pid + stride; if (cn < NCHUNK && tid < 192) sob = ob[cn * 192 + tid]; }
  __syncthreads();

  float entacc = 0.0f, mfacc = 0.0f;
  int buf = 0;
  for (int c = pid; c < NCHUNK; c += stride, buf ^= 1) {
    const int row0 = c * 64;
    const float* ocur = obufA + buf * 256;
    float* onxt = (float*)(obufA + (buf ^ 1) * 256);

    // --- P2: [actor: mask out] + act1 via MFMA (layer 0); stage next ob ---
    if (!role && tid < 64)
      out[OUT_MASK + row0 + tid] = ((int)ocur[tid * 3] == 0) ? 1.0f : 0.0f;
    #pragma unroll
    for (int rt = 0; rt < 4; ++rt) {
      const int rowr = rt * 16 + l15;
      float h0 = ocur[rowr * 3 + 1], h1 = ocur[rowr * 3 + 2];
      uint32_t hp = (l4 == 0) ? cvt_pk_bf16(h0, h1) : 0u;
      bf16x8 hf = frag_u32(hp, 0u, 0u, 0u);
      #pragma unroll
      for (int ct = 0; ct < 2; ++ct) {
        f32x4 a = __builtin_amdgcn_mfma_f32_16x16x32_bf16(w0f[ct], hf, b0i[ct], 0, 0, 0);
        u32x2 w;
        w[0] = cvt_pk_bf16(fmaxf(a[0], 0.0f), fmaxf(a[1], 0.0f));
        w[1] = cvt_pk_bf16(fmaxf(a[2], 0.0f), fmaxf(a[3], 0.0f));
        *(u32x2*)(smem + L_ACT1 + rowr * 512 +
                  ((colbase * 2 + ct * 32 + 8 * l4) ^ SWZ(rowr))) = w;
      }
    }
    if (tid < 192) onxt[tid] = sob;
    { int c2 = c + 2 * stride; if (c2 < NCHUNK && tid < 192) sob = ob[c2 * 192 + tid]; }
    __syncthreads();                              // B2: act1 + onxt ready

    // --- P3: transposed GEMM1 (acc' rows = W1-cols, cols = chunk rows) ---
    #pragma unroll 1
    for (int rtp = 0; rtp < 2; ++rtp) {
      f32x4 acc[2][2];                            // [rt(16-row tile)][ct]
      #pragma unroll
      for (int rt = 0; rt < 2; ++rt)
        #pragma unroll
        for (int ct = 0; ct < 2; ++ct) acc[rt][ct] = b1i[ct];
      const int rB0 = rtp * 32 + l15, rB1 = rB0 + 16;
      #pragma unroll
      for (int ks = 0; ks < 8; ++ks) {
        const int cb = ks * 64 + 16 * l4;
        bf16x8 a0 = *(const bf16x8*)(smem + L_ACT1 + rB0 * 512 + (cb ^ SWZ(rB0)));
        bf16x8 a1 = *(const bf16x8*)(smem + L_ACT1 + rB1 * 512 + (cb ^ SWZ(rB1)));
        acc[0][0] = __builtin_amdgcn_mfma_f32_16x16x32_bf16(bh[0][ks], a0, acc[0][0], 0, 0, 0);
        acc[0][1] = __builtin_amdgcn_mfma_f32_16x16x32_bf16(bh[1][ks], a0, acc[0][1], 0, 0, 0);
        acc[1][0] = __builtin_amdgcn_mfma_f32_16x16x32_bf16(bh[0][ks], a1, acc[1][0], 0, 0, 0);
        acc[1][1] = __builtin_amdgcn_mfma_f32_16x16x32_bf16(bh[1][ks], a1, acc[1][1], 0, 0, 0);
      }
      if (!role) {
        // actor epilogue: relu -> within-lane pack -> b64 store (act2[row][k] swizzled)
        #pragma unroll
        for (int rt = 0; rt < 2; ++rt) {
          const int row = rtp * 32 + rt * 16 + l15;
          const int sw = SWZ(row);
          #pragma unroll
          for (int ct = 0; ct < 2; ++ct) {
            u32x2 w;
            w[0] = cvt_pk_bf16(fmaxf(acc[rt][ct][0], 0.0f), fmaxf(acc[rt][ct][1], 0.0f));
            w[1] = cvt_pk_bf16(fmaxf(acc[rt][ct][2], 0.0f), fmaxf(acc[rt][ct][3], 0.0f));
            *(u32x2*)(smem + L_ACT2 + row * 512 +
                      ((colbase * 2 + ct * 32 + 8 * l4) ^ sw)) = w;
          }
        }
      } else {
        // critic epilogue: fused head, within-lane dot then l4-reduction
        #pragma unroll
        for (int rt = 0; rt < 2; ++rt) {
          float p = 0.0f;
          #pragma unroll
          for (int ct = 0; ct < 2; ++ct)
            #pragma unroll
            for (int r = 0; r < 4; ++r)
              p = fmaf(fmaxf(acc[rt][ct][r], 0.0f), w2r[ct][r], p);
          p += __shfl_xor(p, 16);
          p += __shfl_xor(p, 32);
          if (l4 == 0) vbuf[wave * 64 + rtp * 32 + rt * 16 + l15] = p;
        }
      }
    }
    // pre-B3 captures from ocur (next P2 overwrites this buffer)
    float mk0 = 0.0f, mk1 = 0.0f, o0w0 = 0.0f;
    if (!role) {
      const int rt4 = wave & 3, hf2 = wave >> 2;
      const int rl0 = rt4 * 16 + 4 * l4 + hf2 * 2;
      mk0 = ocur[rl0 * 3];
      mk1 = ocur[(rl0 + 1) * 3];
    } else if (wave == 0) o0w0 = ocur[lane * 3];
    __syncthreads();                              // B3: act2 / vbuf ready

    // --- P4 ---
    if (!role) {
      // actor head on ALL 8 waves: rt4 = wave&3, each wave softmaxes 2 rows
      const int rt4 = wave & 3, hf2 = wave >> 2;
      const int rowA = rt4 * 16 + l15;
      const int swA = SWZ(rowA), swW = SWZ(l15);
      f32x4 ae = {b2lane, b2lane, b2lane, b2lane}, ao = {0.f, 0.f, 0.f, 0.f};
      #pragma unroll
      for (int ks = 0; ks < 8; ks += 2) {
        const int cb0 = ks * 64 + 16 * l4, cb1 = cb0 + 64;
        bf16x8 a0 = *(const bf16x8*)(smem + L_ACT2 + rowA * 512 + (cb0 ^ swA));
        bf16x8 a1 = *(const bf16x8*)(smem + L_ACT2 + rowA * 512 + (cb1 ^ swA));
        bf16x8 w0h = *(const bf16x8*)(smem + L_W2H + l15 * 512 + (cb0 ^ swW));
        bf16x8 w1h = *(const bf16x8*)(smem + L_W2H + l15 * 512 + (cb1 ^ swW));
        ae = __builtin_amdgcn_mfma_f32_16x16x32_bf16(a0, w0h, ae, 0, 0, 0);
        ao = __builtin_amdgcn_mfma_f32_16x16x32_bf16(a1, w1h, ao, 0, 0, 0);
      }
      float mks[2] = { mk0, mk1 };
      #pragma unroll
      for (int r2 = 0; r2 < 2; ++r2) {
        const int r = hf2 * 2 + r2;
        const int rl = rt4 * 16 + 4 * l4 + r;
        float x = ae[r] + ao[r];
        float m = red16_max(x);
        float e = __expf(x - m);
        float s = red16_sum(e);
        float t = red16_sum(e * (x - m));
        float ls = __logf(s);
        float mfr = ((int)mks[r2] == 0) ? 1.0f : 0.0f;
        int av = action[row0 + rl];
        if (l15 == av) out[row0 + rl] = (x - m - ls) * mfr;
        if (l15 == 0) { entacc += (ls - t / s) * mfr; mfacc += mfr; }
      }
    } else {
      // critic: wave 0 sums partials + masked segment-sum atomics
      if (wave == 0) {
        float v = 0.0f;
        #pragma unroll
        for (int w = 0; w < 8; ++w) v += vbuf[w * 64 + lane];
        if ((int)o0w0 == 0) {
          int g = graph_ids[c * 4 + (lane >> 4)];
          atomicAdd(&out[OUT_VP + g * 16 + (lane & 15)], (v + cb2v) * (1.0f / 50000.0f));
        }
      }
    }
    // no end barrier: next P2 writes act1/obuf[buf] only; P4 reads act2/W2H/vbuf
    // (disjoint) and captured registers; vbuf/act1 reuse fenced by next B2.
  }
  // entropy num/den -> global atomics (actor blocks only; block-uniform branch)
  if (!role) {
    #pragma unroll
    for (int d = 1; d < 64; d <<= 1) { entacc += __shfl_xor(entacc, d); mfacc += __shfl_xor(mfacc, d); }
    if (lane == 0) { went[wave] = entacc; wmf[wave] = mfacc; }
    __syncthreads();
    if (tid == 0) {
      float e = 0.f, m = 0.f;
      #pragma unroll
      for (int i = 0; i < 8; ++i) { e += went[i]; m += wmf[i]; }
      atomicAdd(&wsf[0], e); atomicAdd(&wsf[1], m);
    }
  }
}

extern "C" void kernel_launch(void* const* d_in, const int* in_sizes, int n_in,
                              void* d_out, int out_size, void* d_ws, size_t ws_size,
                              hipStream_t stream) {
  const float* ob     = (const float*)d_in[0];
  const int*   action = (const int*)d_in[1];
  const int*   gids   = (const int*)d_in[2];
  const float* aW0 = (const float*)d_in[3],  *ab0 = (const float*)d_in[4];
  const float* aW1 = (const float*)d_in[5],  *ab1 = (const float*)d_in[6];
  const float* aW2 = (const float*)d_in[7],  *ab2 = (const float*)d_in[8];
  const float* cW0 = (const float*)d_in[9],  *cb0 = (const float*)d_in[10];
  const float* cW1 = (const float*)d_in[11], *cb1 = (const float*)d_in[12];
  const float* cW2 = (const float*)d_in[13], *cb2 = (const float*)d_in[14];
  float* out = (float*)d_out;
  float* wsf = (float*)d_ws;

  zero_kernel<<<2, 512, 0, stream>>>(out, wsf);
  ac_main<<<1024, 512, L_SZ, stream>>>(ob, action, gids, aW0, ab0, aW1, ab1, aW2, ab2,
                                       cW0, cb0, cW1, cb1, cW2, cb2, out, wsf);
  final_kernel<<<1, 64, 0, stream>>>(out, wsf);
}